// Round 2
// baseline (32073.871 us; speedup 1.0000x reference)
//
#include <hip/hip_runtime.h>
#include <cstddef>
#include <cstdint>

// Problem constants
#define BATCH 128
#define TSTEPS 256
#define IN_DIM 128
#define HID 512
#define GATES 2048   // 4*HID

// ---------------------------------------------------------------------------
// Weight transpose: in (R x C) row-major -> out (C x R) row-major
// ---------------------------------------------------------------------------
__global__ __launch_bounds__(256) void transpose_kernel(const float* __restrict__ in,
                                                        float* __restrict__ out,
                                                        int R, int C) {
  __shared__ float tile[32][33];
  int c0 = blockIdx.x * 32, r0 = blockIdx.y * 32;
  int tx = threadIdx.x & 31;
  int ty = threadIdx.x >> 5;   // 0..7
#pragma unroll
  for (int i = 0; i < 4; ++i)
    tile[ty + 8 * i][tx] = in[(size_t)(r0 + ty + 8 * i) * C + (c0 + tx)];
  __syncthreads();
#pragma unroll
  for (int i = 0; i < 4; ++i)
    out[(size_t)(c0 + ty + 8 * i) * R + (r0 + tx)] = tile[tx][ty + 8 * i];
}

// ---------------------------------------------------------------------------
// Zero-fill
// ---------------------------------------------------------------------------
__global__ void zero_kernel(float* __restrict__ p, int n) {
  int i = blockIdx.x * 256 + threadIdx.x;
  if (i < n) p[i] = 0.f;
}

// ---------------------------------------------------------------------------
// preds[:,0,:] = x[:,1,:]
// ---------------------------------------------------------------------------
__global__ void copy_pred0_kernel(const float* __restrict__ x, float* __restrict__ preds) {
  int i = blockIdx.x * 256 + threadIdx.x;   // 128*128 threads
  if (i >= BATCH * IN_DIM) return;
  int b = i >> 7, ii = i & 127;
  preds[(size_t)b * TSTEPS * IN_DIM + ii] = x[(size_t)b * TSTEPS * IN_DIM + IN_DIM + ii];
}

// ---------------------------------------------------------------------------
// Fused LSTM cell step.
//   z_g[b, j + g*512] = base + sum_k xin[b,k]*WT_ih[k][j+g*512]
//                            + sum_k hprev[b,k]*WT_hh[k][j+g*512]
//   base = bias (PRE=false) or precomputed row pre[b][...] (PRE=true)
// Tile: 16 batch x 16 j-cols, 4-way K split. 1024 threads, grid (32, 8).
// ---------------------------------------------------------------------------
template <int KX, bool PRE>
__global__ __launch_bounds__(1024) void lstm_cell_kernel(
    const float* __restrict__ xin, int ld_x,
    const float* __restrict__ hprev, int ld_h,
    const float* __restrict__ WT_ih,      // [KX][2048]
    const float* __restrict__ WT_hh,      // [512][2048]
    const float* __restrict__ bias_or_pre,// PRE ? [128][2048] : [2048]
    float* __restrict__ c_state,          // [128][512] in-place
    float* __restrict__ hout, int ld_hout)
{
  constexpr int XS = (KX > 0) ? KX : 1;
  __shared__ float xs[16][XS];
  __shared__ float hs[16][HID];
  __shared__ float part[16][16][4][4];   // [tb][tj][ks][gate]

  int tid = threadIdx.x;
  int tj = tid & 15;
  int tb = (tid >> 4) & 15;
  int ks = tid >> 8;                      // 0..3
  int b0 = blockIdx.y * 16;
  int j  = blockIdx.x * 16 + tj;

  if (KX > 0) {
    for (int idx = tid; idx < 16 * XS; idx += 1024) {
      int r = idx / XS, c = idx - r * XS;
      xs[r][c] = xin[(size_t)(b0 + r) * ld_x + c];
    }
  }
  for (int idx = tid; idx < 16 * HID; idx += 1024) {
    int r = idx >> 9, c = idx & (HID - 1);
    hs[r][c] = hprev[(size_t)(b0 + r) * ld_h + c];
  }
  __syncthreads();

  float ai = 0.f, af = 0.f, ag = 0.f, ao = 0.f;
  if (KX > 0) {
#pragma unroll 4
    for (int k = ks; k < KX; k += 4) {
      float xv = xs[tb][k];
      const float* w = WT_ih + (size_t)k * GATES + j;
      ai = fmaf(xv, w[0], ai);
      af = fmaf(xv, w[512], af);
      ag = fmaf(xv, w[1024], ag);
      ao = fmaf(xv, w[1536], ao);
    }
  }
#pragma unroll 4
  for (int k = ks; k < HID; k += 4) {
    float hv = hs[tb][k];
    const float* w = WT_hh + (size_t)k * GATES + j;
    ai = fmaf(hv, w[0], ai);
    af = fmaf(hv, w[512], af);
    ag = fmaf(hv, w[1024], ag);
    ao = fmaf(hv, w[1536], ao);
  }
  part[tb][tj][ks][0] = ai;
  part[tb][tj][ks][1] = af;
  part[tb][tj][ks][2] = ag;
  part[tb][tj][ks][3] = ao;
  __syncthreads();

  if (tid < 256) {
    int tj2 = tid & 15, tb2 = tid >> 4;
    int jj = blockIdx.x * 16 + tj2;
    int b  = b0 + tb2;
    float zi, zf, zg, zo;
    if (PRE) {
      const float* p = bias_or_pre + (size_t)b * GATES;
      zi = p[jj]; zf = p[jj + 512]; zg = p[jj + 1024]; zo = p[jj + 1536];
    } else {
      zi = bias_or_pre[jj];        zf = bias_or_pre[jj + 512];
      zg = bias_or_pre[jj + 1024]; zo = bias_or_pre[jj + 1536];
    }
#pragma unroll
    for (int s = 0; s < 4; ++s) {
      zi += part[tb2][tj2][s][0];
      zf += part[tb2][tj2][s][1];
      zg += part[tb2][tj2][s][2];
      zo += part[tb2][tj2][s][3];
    }
    float ig = 1.f / (1.f + __expf(-zi));
    float fg = 1.f / (1.f + __expf(-zf));
    float gg = tanhf(zg);
    float og = 1.f / (1.f + __expf(-zo));
    size_t ci = (size_t)b * HID + jj;
    float c = fg * c_state[ci] + ig * gg;
    c_state[ci] = c;
    hout[(size_t)b * ld_hout + jj] = og * tanhf(c);
  }
}

// ---------------------------------------------------------------------------
// Generic tiled GEMM: C[M,N] = A[M,K] @ WT[K,N] + bias[N]
//   mode 0: plain      mode 1: relu      mode 2: preds time-shift write
// BM=BN=64, BK=16, 256 threads, 4x4 per thread.
// ---------------------------------------------------------------------------
__global__ __launch_bounds__(256) void gemm_bias_kernel(
    const float* __restrict__ A, int lda,
    const float* __restrict__ WT, int ldw,
    const float* __restrict__ bias,
    float* __restrict__ C,
    int M, int N, int K, int mode)
{
  __shared__ float As[16][64];
  __shared__ float Ws[16][64];
  int tid = threadIdx.x;
  int tx = tid & 15;       // n dir
  int ty = tid >> 4;       // m dir
  int n0 = blockIdx.x * 64;
  int m0 = blockIdx.y * 64;
  float acc[4][4] = {};

  for (int kb = 0; kb < K; kb += 16) {
    {
      int k = tid & 15;
      int mb = tid >> 4;
#pragma unroll
      for (int i = 0; i < 4; ++i) {
        int m = mb + i * 16;
        As[k][m] = A[(size_t)(m0 + m) * lda + kb + k];
      }
    }
    {
      int n4 = (tid & 15) * 4;
      int k = tid >> 4;
      float4 v = *reinterpret_cast<const float4*>(&WT[(size_t)(kb + k) * ldw + n0 + n4]);
      *reinterpret_cast<float4*>(&Ws[k][n4]) = v;
    }
    __syncthreads();
#pragma unroll
    for (int k = 0; k < 16; ++k) {
      float4 av = *reinterpret_cast<const float4*>(&As[k][ty * 4]);
      float4 wv = *reinterpret_cast<const float4*>(&Ws[k][tx * 4]);
      float a[4] = {av.x, av.y, av.z, av.w};
      float w[4] = {wv.x, wv.y, wv.z, wv.w};
#pragma unroll
      for (int i = 0; i < 4; ++i)
#pragma unroll
        for (int jj = 0; jj < 4; ++jj) acc[i][jj] = fmaf(a[i], w[jj], acc[i][jj]);
    }
    __syncthreads();
  }

#pragma unroll
  for (int i = 0; i < 4; ++i) {
    int m = m0 + ty * 4 + i;
    if (mode == 2) {
      int t = m & (TSTEPS - 1);
      if (t == TSTEPS - 1) continue;
      int b = m >> 8;
      float* crow = C + (size_t)b * TSTEPS * IN_DIM + (size_t)(t + 1) * IN_DIM;
#pragma unroll
      for (int jj = 0; jj < 4; ++jj) {
        int n = n0 + tx * 4 + jj;
        crow[n] = acc[i][jj] + bias[n];
      }
    } else {
      float* crow = C + (size_t)m * N;
#pragma unroll
      for (int jj = 0; jj < 4; ++jj) {
        int n = n0 + tx * 4 + jj;
        float v = acc[i][jj] + bias[n];
        if (mode == 1) v = fmaxf(v, 0.f);
        crow[n] = v;
      }
    }
  }
}

// ---------------------------------------------------------------------------
// Host-side launch
// ---------------------------------------------------------------------------
extern "C" void kernel_launch(void* const* d_in, const int* in_sizes, int n_in,
                              void* d_out, int out_size, void* d_ws, size_t ws_size,
                              hipStream_t stream) {
  (void)in_sizes; (void)n_in; (void)out_size;

  const float* x        = (const float*)d_in[0];
  const float* enc_Wih0 = (const float*)d_in[1];
  const float* enc_Whh0 = (const float*)d_in[2];
  const float* enc_b0   = (const float*)d_in[3];
  const float* enc_Wih1 = (const float*)d_in[4];
  const float* enc_Whh1 = (const float*)d_in[5];
  const float* enc_b1   = (const float*)d_in[6];
  const float* dec_Wih0 = (const float*)d_in[7];
  const float* dec_Whh0 = (const float*)d_in[8];
  const float* dec_b0   = (const float*)d_in[9];
  const float* dec_Wih1 = (const float*)d_in[10];
  const float* dec_Whh1 = (const float*)d_in[11];
  const float* dec_b1   = (const float*)d_in[12];
  const float* fc_W     = (const float*)d_in[13];
  const float* fc_b     = (const float*)d_in[14];
  const float* cls1_W   = (const float*)d_in[15];
  const float* cls1_b   = (const float*)d_in[16];
  const float* cls2_W   = (const float*)d_in[17];
  const float* cls2_b   = (const float*)d_in[18];

  float* out_dec   = (float*)d_out;                              // (B,T,I)
  float* out_preds = (float*)d_out + (size_t)BATCH * TSTEPS * IN_DIM;

  // ---- workspace layout (floats). Requires ~237 MB. ----
  float* ws = (float*)d_ws;
  size_t off = 0;
  float* WT_eih0 = ws + off; off += (size_t)IN_DIM * GATES;   // [128][2048]
  float* WT_ehh0 = ws + off; off += (size_t)HID * GATES;      // [512][2048]
  float* WT_eih1 = ws + off; off += (size_t)HID * GATES;
  float* WT_ehh1 = ws + off; off += (size_t)HID * GATES;
  float* WT_dih0 = ws + off; off += (size_t)HID * GATES;
  float* WT_dhh0 = ws + off; off += (size_t)HID * GATES;
  float* WT_dih1 = ws + off; off += (size_t)HID * GATES;
  float* WT_dhh1 = ws + off; off += (size_t)HID * GATES;
  float* WT_fc   = ws + off; off += (size_t)HID * IN_DIM;     // [512][128]
  float* WT_cls1 = ws + off; off += (size_t)HID * HID;        // [512][512]
  float* WT_cls2 = ws + off; off += (size_t)HID * IN_DIM;     // [512][128]
  float* E0      = ws + off; off += (size_t)BATCH * TSTEPS * HID;  // enc layer0 h, (B,T,E)
  float* E1      = ws + off; off += (size_t)BATCH * TSTEPS * HID;  // enc layer1 h
  float* H1      = ws + off; off += (size_t)BATCH * TSTEPS * HID;  // dec layer1 h
  float* zin0    = ws + off; off += (size_t)BATCH * GATES;         // dec layer0 input preact
  float* states  = ws + off;                                       // contiguous zero region:
  float* hz   = states;                 // [128][512] zeros (h at t=-1)
  float* c0   = states + 1 * 65536;     // enc0 c
  float* c1   = states + 2 * 65536;     // enc1 c
  float* h0a  = states + 3 * 65536;     // dec layer0 h ping
  float* h0b  = states + 4 * 65536;     // dec layer0 h pong
  float* cd0  = states + 5 * 65536;     // dec layer0 c
  float* cd1  = states + 6 * 65536;     // dec layer1 c
  off += 7 * 65536;
  (void)ws_size; // needs off*4 bytes ≈ 237 MB

  const int ldE = TSTEPS * HID;    // 131072, row stride (batch) inside (B,T,H) buffers
  const int ldX = TSTEPS * IN_DIM; // 32768

  // 1. zero states
  {
    int n = 7 * 65536;
    zero_kernel<<<dim3((n + 255) / 256), dim3(256), 0, stream>>>(states, n);
  }
  // 2. transposes: W (R x C) -> WT (C x R)
  transpose_kernel<<<dim3(IN_DIM / 32, GATES / 32), 256, 0, stream>>>(enc_Wih0, WT_eih0, GATES, IN_DIM);
  transpose_kernel<<<dim3(HID / 32, GATES / 32), 256, 0, stream>>>(enc_Whh0, WT_ehh0, GATES, HID);
  transpose_kernel<<<dim3(HID / 32, GATES / 32), 256, 0, stream>>>(enc_Wih1, WT_eih1, GATES, HID);
  transpose_kernel<<<dim3(HID / 32, GATES / 32), 256, 0, stream>>>(enc_Whh1, WT_ehh1, GATES, HID);
  transpose_kernel<<<dim3(HID / 32, GATES / 32), 256, 0, stream>>>(dec_Wih0, WT_dih0, GATES, HID);
  transpose_kernel<<<dim3(HID / 32, GATES / 32), 256, 0, stream>>>(dec_Whh0, WT_dhh0, GATES, HID);
  transpose_kernel<<<dim3(HID / 32, GATES / 32), 256, 0, stream>>>(dec_Wih1, WT_dih1, GATES, HID);
  transpose_kernel<<<dim3(HID / 32, GATES / 32), 256, 0, stream>>>(dec_Whh1, WT_dhh1, GATES, HID);
  transpose_kernel<<<dim3(HID / 32, IN_DIM / 32), 256, 0, stream>>>(fc_W, WT_fc, IN_DIM, HID);
  transpose_kernel<<<dim3(HID / 32, HID / 32), 256, 0, stream>>>(cls1_W, WT_cls1, HID, HID);
  transpose_kernel<<<dim3(HID / 32, IN_DIM / 32), 256, 0, stream>>>(cls2_W, WT_cls2, IN_DIM, HID);

  dim3 cellGrid(HID / 16, BATCH / 16);  // (32, 8)
  dim3 cellBlk(1024);

  // 3. encoder layer 0: h state lives in E0 rows
  for (int t = 0; t < TSTEPS; ++t) {
    const float* hp = (t == 0) ? hz : (E0 + (size_t)(t - 1) * HID);
    int ldh = (t == 0) ? HID : ldE;
    lstm_cell_kernel<IN_DIM, false><<<cellGrid, cellBlk, 0, stream>>>(
        x + (size_t)t * IN_DIM, ldX, hp, ldh,
        WT_eih0, WT_ehh0, enc_b0, c0, E0 + (size_t)t * HID, ldE);
  }
  // 4. encoder layer 1
  for (int t = 0; t < TSTEPS; ++t) {
    const float* hp = (t == 0) ? hz : (E1 + (size_t)(t - 1) * HID);
    int ldh = (t == 0) ? HID : ldE;
    lstm_cell_kernel<HID, false><<<cellGrid, cellBlk, 0, stream>>>(
        E0 + (size_t)t * HID, ldE, hp, ldh,
        WT_eih1, WT_ehh1, enc_b1, c1, E1 + (size_t)t * HID, ldE);
  }
  // 5. zin0 = z @ dec_Wih0^T + dec_b0   (z = E1[:, T-1, :])
  gemm_bias_kernel<<<dim3(GATES / 64, BATCH / 64), 256, 0, stream>>>(
      E1 + (size_t)(TSTEPS - 1) * HID, ldE, WT_dih0, GATES, dec_b0, zin0,
      BATCH, GATES, HID, 0);
  // 6. decoder
  float* h0bufs[2] = {h0a, h0b};
  for (int t = 0; t < TSTEPS; ++t) {
    float* h0w = h0bufs[t & 1];
    const float* h0r = h0bufs[(t & 1) ^ 1];   // zeroed at t=0
    lstm_cell_kernel<0, true><<<cellGrid, cellBlk, 0, stream>>>(
        nullptr, 0, h0r, HID,
        nullptr, WT_dhh0, zin0, cd0, h0w, HID);
    const float* h1p = (t == 0) ? hz : (H1 + (size_t)(t - 1) * HID);
    int ldh1 = (t == 0) ? HID : ldE;
    lstm_cell_kernel<HID, false><<<cellGrid, cellBlk, 0, stream>>>(
        h0w, HID, h1p, ldh1,
        WT_dih1, WT_dhh1, dec_b1, cd1, H1 + (size_t)t * HID, ldE);
  }
  // 7. dec output: out_dec = H1 @ fc_W^T + fc_b   (rows r = b*T+t)
  gemm_bias_kernel<<<dim3(IN_DIM / 64, (BATCH * TSTEPS) / 64), 256, 0, stream>>>(
      H1, HID, WT_fc, IN_DIM, fc_b, out_dec,
      BATCH * TSTEPS, IN_DIM, HID, 0);
  // 8. preds: P1 = relu(E1 @ cls1^T + b1)   (reuse E0 as P1)
  gemm_bias_kernel<<<dim3(HID / 64, (BATCH * TSTEPS) / 64), 256, 0, stream>>>(
      E1, HID, WT_cls1, HID, cls1_b, E0,
      BATCH * TSTEPS, HID, HID, 1);
  // 9. preds final GEMM with time-shift write
  gemm_bias_kernel<<<dim3(IN_DIM / 64, (BATCH * TSTEPS) / 64), 256, 0, stream>>>(
      E0, HID, WT_cls2, IN_DIM, cls2_b, out_preds,
      BATCH * TSTEPS, IN_DIM, HID, 2);
  // 10. preds[:,0,:] = x[:,1,:]
  copy_pred0_kernel<<<dim3((BATCH * IN_DIM + 255) / 256), 256, 0, stream>>>(x, out_preds);
}

// Round 3
// 23513.527 us; speedup vs baseline: 1.3641x; 1.3641x over previous
//
#include <hip/hip_runtime.h>
#include <hip/hip_bf16.h>
#include <hip/hip_cooperative_groups.h>
#include <cstddef>
#include <cstdint>

namespace cg = cooperative_groups;

#define BATCH 128
#define TSTEPS 256
#define IN_DIM 128
#define HID 512
#define GATES 2048
#define HSZ (BATCH * HID)   // 65536 elems, one [128][512] state

typedef __attribute__((ext_vector_type(8))) short short8;   // 8 bf16 = 4 VGPR
typedef __attribute__((ext_vector_type(4))) float f32x4;
typedef __hip_bfloat16 bf16;

__device__ __forceinline__ float sigf(float x) { return 1.f / (1.f + __expf(-x)); }

// ---------------------------------------------------------------------------
// Zero-fill (states region)
// ---------------------------------------------------------------------------
__global__ void zero_kernel(float* __restrict__ p, int n) {
  int i = blockIdx.x * 256 + threadIdx.x;
  if (i < n) p[i] = 0.f;
}

// ---------------------------------------------------------------------------
// fp32 -> bf16 matrix convert with output stride/offset (for [g][kx|kh] concat)
// ---------------------------------------------------------------------------
__global__ void f2b_mat(const float* __restrict__ in, bf16* __restrict__ out,
                        int rows, int cols, int old, int ooff) {
  int i = blockIdx.x * 256 + threadIdx.x;
  if (i >= rows * cols) return;
  int r = i / cols, c = i - r * cols;
  out[(size_t)r * old + ooff + c] = __float2bfloat16(in[i]);
}

// ---------------------------------------------------------------------------
// preds[:,0,:] = x[:,1,:]
// ---------------------------------------------------------------------------
__global__ void copy_pred0_kernel(const float* __restrict__ x, float* __restrict__ preds) {
  int i = blockIdx.x * 256 + threadIdx.x;
  if (i >= BATCH * IN_DIM) return;
  int b = i >> 7, ii = i & 127;
  preds[(size_t)b * TSTEPS * IN_DIM + ii] = x[(size_t)b * TSTEPS * IN_DIM + IN_DIM + ii];
}

// ---------------------------------------------------------------------------
// One LSTM cell step for one layer, executed by one block (of the layer's 128).
// Block covers 32 batches x 16 hidden cols (x 4 gates). 8 waves:
//   wave w: gate = w&3, bt = w>>2 ; computes one 16x16 MFMA tile over K.
// A-frag: rows = batch (lane&15), k = (lane>>4)*8+i  -> 16B global loads
// B-frag: rows = weight row g*512+jh (lane&15), same k -> 16B global loads
//   (weights stored [2048][KX+512] bf16, g-major = original torch layout)
// Gates exchanged via 8KB LDS zbuf; epilogue does sigmoid/tanh + c/h update.
// ---------------------------------------------------------------------------
__device__ __forceinline__ void lstm_step(
    const bf16* __restrict__ xin, int xld, int KX,  // input part (k < KX)
    const bf16* __restrict__ hin,                   // [128][512] h state in
    const bf16* __restrict__ W,                     // [2048][KX+512]
    const float* __restrict__ bias,                 // [2048]
    float* __restrict__ cst,                        // [128][512] fp32, in-place
    bf16* __restrict__ hout,                        // [128][512] h state out
    bf16* __restrict__ seqout,                      // optional [(b*256+t)][512]
    int t, int blk, float* zbuf)                    // zbuf: [2][4][16][16] LDS
{
  const int jg = blk & 31;   // 32 hidden-col groups
  const int bg = blk >> 5;   // 4 batch groups
  const int b0 = bg * 32;
  const int jh0 = jg * 16;
  const int tid = threadIdx.x;
  const int w = tid >> 6;
  const int lane = tid & 63;
  const int gate = w & 3, bt = w >> 2;
  const int arow = b0 + bt * 16 + (lane & 15);
  const int brow = gate * HID + jh0 + (lane & 15);
  const int kb = (lane >> 4) * 8;
  const int K = KX + HID;

  f32x4 acc = {0.f, 0.f, 0.f, 0.f};
  const bf16* wrow = W + (size_t)brow * K;
#pragma unroll 4
  for (int kk = 0; kk < KX; kk += 32) {
    short8 a = *(const short8*)(xin + (size_t)arow * xld + kk + kb);
    short8 b = *(const short8*)(wrow + kk + kb);
    acc = __builtin_amdgcn_mfma_f32_16x16x32_bf16(a, b, acc, 0, 0, 0);
  }
  const bf16* hrow = hin + (size_t)arow * HID;
  const bf16* wrow2 = wrow + KX;
#pragma unroll 4
  for (int kk = 0; kk < HID; kk += 32) {
    short8 a = *(const short8*)(hrow + kk + kb);
    short8 b = *(const short8*)(wrow2 + kk + kb);
    acc = __builtin_amdgcn_mfma_f32_16x16x32_bf16(a, b, acc, 0, 0, 0);
  }
  // write z tile: D row=(lane>>4)*4+r (batch), col=lane&15 (hidden col)
  float* zb = zbuf + (bt * 4 + gate) * 256;
#pragma unroll
  for (int r = 0; r < 4; ++r)
    zb[((lane >> 4) * 4 + r) * 16 + (lane & 15)] = acc[r];
  __syncthreads();
  // epilogue: 512 threads -> 32 batches x 16 hidden cols
  {
    const int bt2 = tid >> 8, br = (tid >> 4) & 15, jh = tid & 15;
    const int b = b0 + bt2 * 16 + br;
    const int j = jh0 + jh;
    const float* zq = zbuf + bt2 * 1024 + br * 16 + jh;
    float zi = zq[0] + bias[j];
    float zf = zq[256] + bias[HID + j];
    float zg = zq[512] + bias[2 * HID + j];
    float zo = zq[768] + bias[3 * HID + j];
    size_t ci = (size_t)b * HID + j;
    float c = sigf(zf) * cst[ci] + sigf(zi) * tanhf(zg);
    cst[ci] = c;
    float h = sigf(zo) * tanhf(c);
    bf16 hb = __float2bfloat16(h);
    hout[ci] = hb;
    if (seqout) seqout[((size_t)b * TSTEPS + t) * HID + j] = hb;
  }
}

struct RecParams {
  const bf16* xb;                 // [128][256][128]
  const bf16 *W0, *W1, *WD0, *WD1;// [2048][640/1024] concat ih|hh
  const float *b0, *b1, *db0, *db1;
  bf16 *S0, *S1, *D0, *D1;        // [2][128][512] ping-pong h states
  float *c0, *c1, *cd0, *cd1;     // [128][512]
  bf16 *E1b, *H1b;                // [32768][512] sequence outputs
};

// ---------------------------------------------------------------------------
// Persistent cooperative recurrence: 256 blocks x 512 threads.
// Blocks 0-127 = layer A (enc0 / dec0), 128-255 = layer B (enc1 / dec1),
// pipelined one step apart; one grid sync per iteration.
// ---------------------------------------------------------------------------
__global__ __launch_bounds__(512) void rec_kernel(RecParams P) {
  cg::grid_group grid = cg::this_grid();
  __shared__ float zbuf[2 * 4 * 16 * 16];
  const int blk = blockIdx.x;
  const bool grp1 = blk >= 128;
  const int lb = grp1 ? blk - 128 : blk;

  // ---- encoder: enc0 at t=it, enc1 at t=it-1 ----
  for (int it = 0; it <= TSTEPS; ++it) {
    if (!grp1) {
      if (it < TSTEPS) {
        int t = it;
        lstm_step(P.xb + (size_t)t * IN_DIM, TSTEPS * IN_DIM, IN_DIM,
                  P.S0 + ((t + 1) & 1) * HSZ, P.W0, P.b0, P.c0,
                  P.S0 + (t & 1) * HSZ, nullptr, t, lb, zbuf);
      }
    } else {
      if (it >= 1) {
        int t = it - 1;
        lstm_step(P.S0 + (t & 1) * HSZ, HID, HID,
                  P.S1 + ((t + 1) & 1) * HSZ, P.W1, P.b1, P.c1,
                  P.S1 + (t & 1) * HSZ, P.E1b, t, lb, zbuf);
      }
    }
    grid.sync();
  }
  // z = enc1 h at t=255 -> lives at S1 parity (255&1)=1, untouched below.
  const bf16* z = P.S1 + HSZ;

  // ---- decoder: dec0 at t=it, dec1 at t=it-1 ----
  for (int it = 0; it <= TSTEPS; ++it) {
    if (!grp1) {
      if (it < TSTEPS) {
        int t = it;
        lstm_step(z, HID, HID,
                  P.D0 + ((t + 1) & 1) * HSZ, P.WD0, P.db0, P.cd0,
                  P.D0 + (t & 1) * HSZ, nullptr, t, lb, zbuf);
      }
    } else {
      if (it >= 1) {
        int t = it - 1;
        lstm_step(P.D0 + (t & 1) * HSZ, HID, HID,
                  P.D1 + ((t + 1) & 1) * HSZ, P.WD1, P.db1, P.cd1,
                  P.D1 + (t & 1) * HSZ, P.H1b, t, lb, zbuf);
      }
    }
    grid.sync();
  }
}

// ---------------------------------------------------------------------------
// Tail MFMA GEMM: out[M][N] = A[M][512] @ W[N][512]^T + bias
// block = 8 waves: wave w covers M-half (w>>2)*64, N-quarter (w&3)*16.
// grid = (N/64, M/128).
//   MODE 0: fp32 out, N=128 (fc -> out_dec)
//   MODE 1: relu, bf16 out, N=512 (cls1 -> P1b)
//   MODE 2: fp32 out, N=128, time-shift rows (cls2 -> out_preds)
// ---------------------------------------------------------------------------
template <int MODE>
__global__ __launch_bounds__(512) void mfma_gemm(
    const bf16* __restrict__ A, const bf16* __restrict__ W,
    const float* __restrict__ bias, void* __restrict__ out)
{
  const int n0 = blockIdx.x * 64, m0 = blockIdx.y * 128;
  const int tid = threadIdx.x, w = tid >> 6, lane = tid & 63;
  const int nq = w & 3, mh = w >> 2;
  const int mb = m0 + mh * 64;
  const int col = n0 + nq * 16 + (lane & 15);
  const int kb = (lane >> 4) * 8;
  const bf16* wrow = W + (size_t)col * HID;

  f32x4 acc[4];
#pragma unroll
  for (int i = 0; i < 4; ++i) acc[i] = (f32x4){0.f, 0.f, 0.f, 0.f};

#pragma unroll 4
  for (int kk = 0; kk < HID; kk += 32) {
    short8 bfr = *(const short8*)(wrow + kk + kb);
#pragma unroll
    for (int i = 0; i < 4; ++i) {
      short8 afr = *(const short8*)(A + (size_t)(mb + i * 16 + (lane & 15)) * HID + kk + kb);
      acc[i] = __builtin_amdgcn_mfma_f32_16x16x32_bf16(afr, bfr, acc[i], 0, 0, 0);
    }
  }
  const float bv = bias[col];
#pragma unroll
  for (int i = 0; i < 4; ++i) {
#pragma unroll
    for (int r = 0; r < 4; ++r) {
      int m = mb + i * 16 + (lane >> 4) * 4 + r;
      float v = acc[i][r] + bv;
      if (MODE == 1) {
        ((bf16*)out)[(size_t)m * HID + col] = __float2bfloat16(fmaxf(v, 0.f));
      } else if (MODE == 0) {
        ((float*)out)[(size_t)m * IN_DIM + col] = v;
      } else {
        int t = m & (TSTEPS - 1), b = m >> 8;
        if (t < TSTEPS - 1)
          ((float*)out)[((size_t)b * TSTEPS + t + 1) * IN_DIM + col] = v;
      }
    }
  }
}

// ---------------------------------------------------------------------------
// Host-side launch
// ---------------------------------------------------------------------------
extern "C" void kernel_launch(void* const* d_in, const int* in_sizes, int n_in,
                              void* d_out, int out_size, void* d_ws, size_t ws_size,
                              hipStream_t stream) {
  (void)in_sizes; (void)n_in; (void)out_size; (void)ws_size;

  const float* x        = (const float*)d_in[0];
  const float* enc_Wih0 = (const float*)d_in[1];
  const float* enc_Whh0 = (const float*)d_in[2];
  const float* enc_b0   = (const float*)d_in[3];
  const float* enc_Wih1 = (const float*)d_in[4];
  const float* enc_Whh1 = (const float*)d_in[5];
  const float* enc_b1   = (const float*)d_in[6];
  const float* dec_Wih0 = (const float*)d_in[7];
  const float* dec_Whh0 = (const float*)d_in[8];
  const float* dec_b0   = (const float*)d_in[9];
  const float* dec_Wih1 = (const float*)d_in[10];
  const float* dec_Whh1 = (const float*)d_in[11];
  const float* dec_b1   = (const float*)d_in[12];
  const float* fc_W     = (const float*)d_in[13];
  const float* fc_b     = (const float*)d_in[14];
  const float* cls1_W   = (const float*)d_in[15];
  const float* cls1_b   = (const float*)d_in[16];
  const float* cls2_W   = (const float*)d_in[17];
  const float* cls2_b   = (const float*)d_in[18];

  float* out_dec   = (float*)d_out;
  float* out_preds = (float*)d_out + (size_t)BATCH * TSTEPS * IN_DIM;

  // ---- workspace carve-up (all sizes 256B-aligned) ----
  char* wsp = (char*)d_ws;
  auto alloc = [&](size_t bytes) { char* p = wsp; wsp += (bytes + 255) & ~(size_t)255; return p; };
  bf16* W0   = (bf16*)alloc((size_t)GATES * 640 * 2);
  bf16* W1   = (bf16*)alloc((size_t)GATES * 1024 * 2);
  bf16* WD0  = (bf16*)alloc((size_t)GATES * 1024 * 2);
  bf16* WD1  = (bf16*)alloc((size_t)GATES * 1024 * 2);
  bf16* Wc1  = (bf16*)alloc((size_t)HID * HID * 2);
  bf16* Wc2  = (bf16*)alloc((size_t)IN_DIM * HID * 2);
  bf16* Wfc  = (bf16*)alloc((size_t)IN_DIM * HID * 2);
  bf16* xb   = (bf16*)alloc((size_t)BATCH * TSTEPS * IN_DIM * 2);
  bf16* E1b  = (bf16*)alloc((size_t)BATCH * TSTEPS * HID * 2);
  bf16* H1b  = (bf16*)alloc((size_t)BATCH * TSTEPS * HID * 2);
  bf16* P1b  = (bf16*)alloc((size_t)BATCH * TSTEPS * HID * 2);
  // contiguous zeroed state region: 4 bf16 ping-pong states + 4 fp32 c states
  char* states = alloc(4 * (2 * HSZ * 2) + 4 * (HSZ * 4));
  bf16* S0 = (bf16*)states;
  bf16* S1 = S0 + 2 * HSZ;
  bf16* D0 = S1 + 2 * HSZ;
  bf16* D1 = D0 + 2 * HSZ;
  float* c0  = (float*)(D1 + 2 * HSZ);
  float* c1  = c0 + HSZ;
  float* cd0 = c1 + HSZ;
  float* cd1 = cd0 + HSZ;

  // 1. zero states (bf16 region + fp32 region = 2 MB = 524288 floats)
  zero_kernel<<<dim3(524288 / 256), dim3(256), 0, stream>>>((float*)states, 524288);

  // 2. weight + x conversions to bf16 ([g][k] layout is the original layout)
  auto conv = [&](const float* in, bf16* outp, int rows, int cols, int old, int ooff) {
    int n = rows * cols;
    f2b_mat<<<dim3((n + 255) / 256), dim3(256), 0, stream>>>(in, outp, rows, cols, old, ooff);
  };
  conv(enc_Wih0, W0, GATES, IN_DIM, 640, 0);
  conv(enc_Whh0, W0, GATES, HID, 640, IN_DIM);
  conv(enc_Wih1, W1, GATES, HID, 1024, 0);
  conv(enc_Whh1, W1, GATES, HID, 1024, HID);
  conv(dec_Wih0, WD0, GATES, HID, 1024, 0);
  conv(dec_Whh0, WD0, GATES, HID, 1024, HID);
  conv(dec_Wih1, WD1, GATES, HID, 1024, 0);
  conv(dec_Whh1, WD1, GATES, HID, 1024, HID);
  conv(cls1_W, Wc1, HID, HID, HID, 0);
  conv(cls2_W, Wc2, IN_DIM, HID, HID, 0);
  conv(fc_W, Wfc, IN_DIM, HID, HID, 0);
  conv(x, xb, BATCH * TSTEPS, IN_DIM, IN_DIM, 0);

  // 3. persistent cooperative recurrence (768 LSTM steps, 514 grid syncs)
  RecParams P;
  P.xb = xb; P.W0 = W0; P.W1 = W1; P.WD0 = WD0; P.WD1 = WD1;
  P.b0 = enc_b0; P.b1 = enc_b1; P.db0 = dec_b0; P.db1 = dec_b1;
  P.S0 = S0; P.S1 = S1; P.D0 = D0; P.D1 = D1;
  P.c0 = c0; P.c1 = c1; P.cd0 = cd0; P.cd1 = cd1;
  P.E1b = E1b; P.H1b = H1b;
  void* args[] = {&P};
  hipLaunchCooperativeKernel((void*)rec_kernel, dim3(256), dim3(512), args, 0, stream);

  // 4. tails: cls1 (relu, bf16), cls2 (time-shift), fc
  mfma_gemm<1><<<dim3(HID / 64, (BATCH * TSTEPS) / 128), dim3(512), 0, stream>>>(
      E1b, Wc1, cls1_b, P1b);
  mfma_gemm<2><<<dim3(IN_DIM / 64, (BATCH * TSTEPS) / 128), dim3(512), 0, stream>>>(
      P1b, Wc2, cls2_b, out_preds);
  mfma_gemm<0><<<dim3(IN_DIM / 64, (BATCH * TSTEPS) / 128), dim3(512), 0, stream>>>(
      H1b, Wfc, fc_b, out_dec);

  // 5. preds[:,0,:] = x[:,1,:]
  copy_pred0_kernel<<<dim3((BATCH * IN_DIM + 255) / 256), dim3(256), 0, stream>>>(x, out_preds);
}

// Round 5
// 9137.782 us; speedup vs baseline: 3.5100x; 2.5732x over previous
//
#include <hip/hip_runtime.h>
#include <hip/hip_bf16.h>
#include <cstddef>
#include <cstdint>

#define BATCH 128
#define TSTEPS 256
#define IN_DIM 128
#define HID 512
#define GATES 2048
#define HSZ (BATCH * HID)   // 65536 elems, one [128][512] state

typedef __attribute__((ext_vector_type(8))) short short8;   // 8 bf16 = 4 VGPR
typedef __attribute__((ext_vector_type(4))) float f32x4;
typedef __hip_bfloat16 bf16;

__device__ __forceinline__ float sigf(float x) { return 1.f / (1.f + __expf(-x)); }

// ---------------------------------------------------------------------------
// Zero-fill (states region)
// ---------------------------------------------------------------------------
__global__ void zero_kernel(float* __restrict__ p, int n) {
  int i = blockIdx.x * 256 + threadIdx.x;
  if (i < n) p[i] = 0.f;
}

// ---------------------------------------------------------------------------
// fp32 -> bf16 matrix convert with output stride/offset (for [g][kx|kh] concat)
// ---------------------------------------------------------------------------
__global__ void f2b_mat(const float* __restrict__ in, bf16* __restrict__ out,
                        int rows, int cols, int old, int ooff) {
  int i = blockIdx.x * 256 + threadIdx.x;
  if (i >= rows * cols) return;
  int r = i / cols, c = i - r * cols;
  out[(size_t)r * old + ooff + c] = __float2bfloat16(in[i]);
}

// ---------------------------------------------------------------------------
// preds[:,0,:] = x[:,1,:]
// ---------------------------------------------------------------------------
__global__ void copy_pred0_kernel(const float* __restrict__ x, float* __restrict__ preds) {
  int i = blockIdx.x * 256 + threadIdx.x;
  if (i >= BATCH * IN_DIM) return;
  int b = i >> 7, ii = i & 127;
  preds[(size_t)b * TSTEPS * IN_DIM + ii] = x[(size_t)b * TSTEPS * IN_DIM + IN_DIM + ii];
}

// ---------------------------------------------------------------------------
// One LSTM cell step for one layer, executed by one block (of the layer's 128).
// Block covers 32 batches x 16 hidden cols (x 4 gates). 8 waves:
//   wave w: gate = w&3, bt = w>>2 ; one 16x16 MFMA tile over K.
// A-frag rows = batch, B-frag rows = weight row g*512+jh (original torch
// layout [2048][KX+512] bf16 = already B^T for mfma). Gates exchanged via
// 8KB LDS zbuf; epilogue does sigmoid/tanh + c/h update.
// ---------------------------------------------------------------------------
__device__ __forceinline__ void lstm_step(
    const bf16* __restrict__ xin, int xld, int KX,  // input part (k < KX)
    const bf16* __restrict__ hin,                   // [128][512] h state in
    const bf16* __restrict__ W,                     // [2048][KX+512]
    const float* __restrict__ bias,                 // [2048]
    float* __restrict__ cst,                        // [128][512] fp32, in-place
    bf16* __restrict__ hout,                        // [128][512] h state out
    bf16* __restrict__ seqout,                      // optional [(b*256+t)][512]
    int t, int blk, float* zbuf)                    // zbuf: [2][4][16][16] LDS
{
  const int jg = blk & 31;   // 32 hidden-col groups
  const int bg = blk >> 5;   // 4 batch groups
  const int b0 = bg * 32;
  const int jh0 = jg * 16;
  const int tid = threadIdx.x;
  const int w = tid >> 6;
  const int lane = tid & 63;
  const int gate = w & 3, bt = w >> 2;
  const int arow = b0 + bt * 16 + (lane & 15);
  const int brow = gate * HID + jh0 + (lane & 15);
  const int kb = (lane >> 4) * 8;
  const int K = KX + HID;

  f32x4 acc = {0.f, 0.f, 0.f, 0.f};
  const bf16* wrow = W + (size_t)brow * K;
#pragma unroll 4
  for (int kk = 0; kk < KX; kk += 32) {
    short8 a = *(const short8*)(xin + (size_t)arow * xld + kk + kb);
    short8 b = *(const short8*)(wrow + kk + kb);
    acc = __builtin_amdgcn_mfma_f32_16x16x32_bf16(a, b, acc, 0, 0, 0);
  }
  const bf16* hrow = hin + (size_t)arow * HID;
  const bf16* wrow2 = wrow + KX;
#pragma unroll 4
  for (int kk = 0; kk < HID; kk += 32) {
    short8 a = *(const short8*)(hrow + kk + kb);
    short8 b = *(const short8*)(wrow2 + kk + kb);
    acc = __builtin_amdgcn_mfma_f32_16x16x32_bf16(a, b, acc, 0, 0, 0);
  }
  // write z tile: D row=(lane>>4)*4+r (batch), col=lane&15 (hidden col)
  float* zb = zbuf + (bt * 4 + gate) * 256;
#pragma unroll
  for (int r = 0; r < 4; ++r)
    zb[((lane >> 4) * 4 + r) * 16 + (lane & 15)] = acc[r];
  __syncthreads();
  // epilogue: 512 threads -> 32 batches x 16 hidden cols
  {
    const int bt2 = tid >> 8, br = (tid >> 4) & 15, jh = tid & 15;
    const int b = b0 + bt2 * 16 + br;
    const int j = jh0 + jh;
    const float* zq = zbuf + bt2 * 1024 + br * 16 + jh;
    float zi = zq[0] + bias[j];
    float zf = zq[256] + bias[HID + j];
    float zg = zq[512] + bias[2 * HID + j];
    float zo = zq[768] + bias[3 * HID + j];
    size_t ci = (size_t)b * HID + j;
    float c = sigf(zf) * cst[ci] + sigf(zi) * tanhf(zg);
    cst[ci] = c;
    float h = sigf(zo) * tanhf(c);
    bf16 hb = __float2bfloat16(h);
    hout[ci] = hb;
    if (seqout) seqout[((size_t)b * TSTEPS + t) * HID + j] = hb;
  }
}

struct RecParams {
  const bf16* xb;                 // [128][256][128]
  const bf16 *W0, *W1, *WD0, *WD1;// [2048][640/1024] concat ih|hh
  const float *b0, *b1, *db0, *db1;
  bf16 *S0, *S1, *D0, *D1;        // [2][128][512] ping-pong h states
  float *c0, *c1, *cd0, *cd1;     // [128][512]
  bf16 *E1b, *H1b;                // [32768][512] sequence outputs
};

// ---------------------------------------------------------------------------
// One pipelined iteration = one launch. Blocks 0-127: layer A at t=it,
// blocks 128-255: layer B at t=it-1. Stream ordering between launches
// provides the producer->consumer barrier (replaces grid.sync, which cost
// ~45us/iter from cross-XCD L2 writeback+invalidate).
// phase 0: A=enc0, B=enc1.   phase 1: A=dec0 (xin=z const), B=dec1.
// ---------------------------------------------------------------------------
__global__ __launch_bounds__(512) void step_kernel(RecParams P, int it, int phase) {
  __shared__ float zbuf[2 * 4 * 16 * 16];
  const int blk = blockIdx.x;
  const bool grp1 = blk >= 128;
  const int lb = grp1 ? blk - 128 : blk;

  if (phase == 0) {
    if (!grp1) {
      if (it < TSTEPS) {
        int t = it;
        lstm_step(P.xb + (size_t)t * IN_DIM, TSTEPS * IN_DIM, IN_DIM,
                  P.S0 + ((t + 1) & 1) * HSZ, P.W0, P.b0, P.c0,
                  P.S0 + (t & 1) * HSZ, nullptr, t, lb, zbuf);
      }
    } else if (it >= 1) {
      int t = it - 1;
      lstm_step(P.S0 + (t & 1) * HSZ, HID, HID,
                P.S1 + ((t + 1) & 1) * HSZ, P.W1, P.b1, P.c1,
                P.S1 + (t & 1) * HSZ, P.E1b, t, lb, zbuf);
    }
  } else {
    // z = enc1 h at t=255 (parity 1), untouched during decode
    const bf16* z = P.S1 + HSZ;
    if (!grp1) {
      if (it < TSTEPS) {
        int t = it;
        lstm_step(z, HID, HID,
                  P.D0 + ((t + 1) & 1) * HSZ, P.WD0, P.db0, P.cd0,
                  P.D0 + (t & 1) * HSZ, nullptr, t, lb, zbuf);
      }
    } else if (it >= 1) {
      int t = it - 1;
      lstm_step(P.D0 + (t & 1) * HSZ, HID, HID,
                P.D1 + ((t + 1) & 1) * HSZ, P.WD1, P.db1, P.cd1,
                P.D1 + (t & 1) * HSZ, P.H1b, t, lb, zbuf);
    }
  }
}

// ---------------------------------------------------------------------------
// Tail MFMA GEMM: out[M][N] = A[M][512] @ W[N][512]^T + bias
//   MODE 0: fp32 out, N=128 (fc -> out_dec)
//   MODE 1: relu, bf16 out, N=512 (cls1 -> P1b)
//   MODE 2: fp32 out, N=128, time-shift rows (cls2 -> out_preds)
// ---------------------------------------------------------------------------
template <int MODE>
__global__ __launch_bounds__(512) void mfma_gemm(
    const bf16* __restrict__ A, const bf16* __restrict__ W,
    const float* __restrict__ bias, void* __restrict__ out)
{
  const int n0 = blockIdx.x * 64, m0 = blockIdx.y * 128;
  const int tid = threadIdx.x, w = tid >> 6, lane = tid & 63;
  const int nq = w & 3, mh = w >> 2;
  const int mb = m0 + mh * 64;
  const int col = n0 + nq * 16 + (lane & 15);
  const int kb = (lane >> 4) * 8;
  const bf16* wrow = W + (size_t)col * HID;

  f32x4 acc[4];
#pragma unroll
  for (int i = 0; i < 4; ++i) acc[i] = (f32x4){0.f, 0.f, 0.f, 0.f};

#pragma unroll 4
  for (int kk = 0; kk < HID; kk += 32) {
    short8 bfr = *(const short8*)(wrow + kk + kb);
#pragma unroll
    for (int i = 0; i < 4; ++i) {
      short8 afr = *(const short8*)(A + (size_t)(mb + i * 16 + (lane & 15)) * HID + kk + kb);
      acc[i] = __builtin_amdgcn_mfma_f32_16x16x32_bf16(afr, bfr, acc[i], 0, 0, 0);
    }
  }
  const float bv = bias[col];
#pragma unroll
  for (int i = 0; i < 4; ++i) {
#pragma unroll
    for (int r = 0; r < 4; ++r) {
      int m = mb + i * 16 + (lane >> 4) * 4 + r;
      float v = acc[i][r] + bv;
      if (MODE == 1) {
        ((bf16*)out)[(size_t)m * HID + col] = __float2bfloat16(fmaxf(v, 0.f));
      } else if (MODE == 0) {
        ((float*)out)[(size_t)m * IN_DIM + col] = v;
      } else {
        int t = m & (TSTEPS - 1), b = m >> 8;
        if (t < TSTEPS - 1)
          ((float*)out)[((size_t)b * TSTEPS + t + 1) * IN_DIM + col] = v;
      }
    }
  }
}

// ---------------------------------------------------------------------------
// Host-side launch
// ---------------------------------------------------------------------------
extern "C" void kernel_launch(void* const* d_in, const int* in_sizes, int n_in,
                              void* d_out, int out_size, void* d_ws, size_t ws_size,
                              hipStream_t stream) {
  (void)in_sizes; (void)n_in; (void)out_size; (void)ws_size;

  const float* x        = (const float*)d_in[0];
  const float* enc_Wih0 = (const float*)d_in[1];
  const float* enc_Whh0 = (const float*)d_in[2];
  const float* enc_b0   = (const float*)d_in[3];
  const float* enc_Wih1 = (const float*)d_in[4];
  const float* enc_Whh1 = (const float*)d_in[5];
  const float* enc_b1   = (const float*)d_in[6];
  const float* dec_Wih0 = (const float*)d_in[7];
  const float* dec_Whh0 = (const float*)d_in[8];
  const float* dec_b0   = (const float*)d_in[9];
  const float* dec_Wih1 = (const float*)d_in[10];
  const float* dec_Whh1 = (const float*)d_in[11];
  const float* dec_b1   = (const float*)d_in[12];
  const float* fc_W     = (const float*)d_in[13];
  const float* fc_b     = (const float*)d_in[14];
  const float* cls1_W   = (const float*)d_in[15];
  const float* cls1_b   = (const float*)d_in[16];
  const float* cls2_W   = (const float*)d_in[17];
  const float* cls2_b   = (const float*)d_in[18];

  float* out_dec   = (float*)d_out;
  float* out_preds = (float*)d_out + (size_t)BATCH * TSTEPS * IN_DIM;

  // ---- workspace carve-up (all sizes 256B-aligned) ----
  char* wsp = (char*)d_ws;
  auto alloc = [&](size_t bytes) { char* p = wsp; wsp += (bytes + 255) & ~(size_t)255; return p; };
  bf16* W0   = (bf16*)alloc((size_t)GATES * 640 * 2);
  bf16* W1   = (bf16*)alloc((size_t)GATES * 1024 * 2);
  bf16* WD0  = (bf16*)alloc((size_t)GATES * 1024 * 2);
  bf16* WD1  = (bf16*)alloc((size_t)GATES * 1024 * 2);
  bf16* Wc1  = (bf16*)alloc((size_t)HID * HID * 2);
  bf16* Wc2  = (bf16*)alloc((size_t)IN_DIM * HID * 2);
  bf16* Wfc  = (bf16*)alloc((size_t)IN_DIM * HID * 2);
  bf16* xb   = (bf16*)alloc((size_t)BATCH * TSTEPS * IN_DIM * 2);
  bf16* E1b  = (bf16*)alloc((size_t)BATCH * TSTEPS * HID * 2);
  bf16* H1b  = (bf16*)alloc((size_t)BATCH * TSTEPS * HID * 2);
  bf16* P1b  = (bf16*)alloc((size_t)BATCH * TSTEPS * HID * 2);
  // contiguous zeroed state region: 4 bf16 ping-pong states + 4 fp32 c states
  char* states = alloc(4 * (2 * HSZ * 2) + 4 * (HSZ * 4));
  bf16* S0 = (bf16*)states;
  bf16* S1 = S0 + 2 * HSZ;
  bf16* D0 = S1 + 2 * HSZ;
  bf16* D1 = D0 + 2 * HSZ;
  float* c0  = (float*)(D1 + 2 * HSZ);
  float* c1  = c0 + HSZ;
  float* cd0 = c1 + HSZ;
  float* cd1 = cd0 + HSZ;

  // 1. zero states (bf16 region + fp32 region = 2 MB = 524288 floats)
  zero_kernel<<<dim3(524288 / 256), dim3(256), 0, stream>>>((float*)states, 524288);

  // 2. weight + x conversions to bf16 ([g][k] layout is the original layout)
  auto conv = [&](const float* in, bf16* outp, int rows, int cols, int old, int ooff) {
    int n = rows * cols;
    f2b_mat<<<dim3((n + 255) / 256), dim3(256), 0, stream>>>(in, outp, rows, cols, old, ooff);
  };
  conv(enc_Wih0, W0, GATES, IN_DIM, 640, 0);
  conv(enc_Whh0, W0, GATES, HID, 640, IN_DIM);
  conv(enc_Wih1, W1, GATES, HID, 1024, 0);
  conv(enc_Whh1, W1, GATES, HID, 1024, HID);
  conv(dec_Wih0, WD0, GATES, HID, 1024, 0);
  conv(dec_Whh0, WD0, GATES, HID, 1024, HID);
  conv(dec_Wih1, WD1, GATES, HID, 1024, 0);
  conv(dec_Whh1, WD1, GATES, HID, 1024, HID);
  conv(cls1_W, Wc1, HID, HID, HID, 0);
  conv(cls2_W, Wc2, IN_DIM, HID, HID, 0);
  conv(fc_W, Wfc, IN_DIM, HID, HID, 0);
  conv(x, xb, BATCH * TSTEPS, IN_DIM, IN_DIM, 0);

  // 3. recurrence: one launch per pipelined iteration (stream = the barrier)
  RecParams P;
  P.xb = xb; P.W0 = W0; P.W1 = W1; P.WD0 = WD0; P.WD1 = WD1;
  P.b0 = enc_b0; P.b1 = enc_b1; P.db0 = dec_b0; P.db1 = dec_b1;
  P.S0 = S0; P.S1 = S1; P.D0 = D0; P.D1 = D1;
  P.c0 = c0; P.c1 = c1; P.cd0 = cd0; P.cd1 = cd1;
  P.E1b = E1b; P.H1b = H1b;

  for (int it = 0; it <= TSTEPS; ++it)
    step_kernel<<<dim3(256), dim3(512), 0, stream>>>(P, it, 0);
  for (int it = 0; it <= TSTEPS; ++it)
    step_kernel<<<dim3(256), dim3(512), 0, stream>>>(P, it, 1);

  // 4. tails: cls1 (relu, bf16), cls2 (time-shift), fc
  mfma_gemm<1><<<dim3(HID / 64, (BATCH * TSTEPS) / 128), dim3(512), 0, stream>>>(
      E1b, Wc1, cls1_b, P1b);
  mfma_gemm<2><<<dim3(IN_DIM / 64, (BATCH * TSTEPS) / 128), dim3(512), 0, stream>>>(
      P1b, Wc2, cls2_b, out_preds);
  mfma_gemm<0><<<dim3(IN_DIM / 64, (BATCH * TSTEPS) / 128), dim3(512), 0, stream>>>(
      H1b, Wfc, fc_b, out_dec);

  // 5. preds[:,0,:] = x[:,1,:]
  copy_pred0_kernel<<<dim3((BATCH * IN_DIM + 255) / 256), dim3(256), 0, stream>>>(x, out_preds);
}

// Round 14
// 7125.806 us; speedup vs baseline: 4.5011x; 1.2824x over previous
//
#include <hip/hip_runtime.h>
#include <hip/hip_bf16.h>
#include <cstddef>
#include <cstdint>

#define BATCH 128
#define TSTEPS 256
#define IN_DIM 128
#define HID 512
#define GATES 2048

typedef __attribute__((ext_vector_type(8))) short short8;   // 8 bf16 = 4 VGPR
typedef __attribute__((ext_vector_type(4))) float f32x4;
typedef __hip_bfloat16 bf16;

__device__ __forceinline__ float sigf(float x) { return 1.f / (1.f + __expf(-x)); }

// ---------------------------------------------------------------------------
__global__ void zero_kernel(float* __restrict__ p, int n) {
  int i = blockIdx.x * 256 + threadIdx.x;
  if (i < n) p[i] = 0.f;
}

__global__ void f2b_mat(const float* __restrict__ in, bf16* __restrict__ out,
                        int rows, int cols, int old, int ooff) {
  int i = blockIdx.x * 256 + threadIdx.x;
  if (i >= rows * cols) return;
  int r = i / cols, c = i - r * cols;
  out[(size_t)r * old + ooff + c] = __float2bfloat16(in[i]);
}

__global__ void copy_pred0_kernel(const float* __restrict__ x, float* __restrict__ preds) {
  int i = blockIdx.x * 256 + threadIdx.x;
  if (i >= BATCH * IN_DIM) return;
  int b = i >> 7, ii = i & 127;
  preds[(size_t)b * TSTEPS * IN_DIM + ii] = x[(size_t)b * TSTEPS * IN_DIM + IN_DIM + ii];
}

// ---------------------------------------------------------------------------
// Persistent recurrence kernel. 256 blocks x 512 threads, 1 block/CU (LDS-
// bound), cooperative launch => all co-resident. Blocks 0-127: enc0 then
// dec0 for (bg,jg) tile; blocks 128-255: enc1 then dec1.
// Per block: weight slice (64 gate-rows x K, +16B row pad) stationary in LDS;
// c-state and biases in registers; h exchanged via full sequence buffers in
// global, synchronized with monotonic per-(layer,bg) flag counters:
//   producer: stores -> vmcnt(0) -> barrier -> tid0 {agent release fence,
//             flag += 1}
//   consumer: tid0 {relaxed spin, agent acquire fence} -> barrier -> loads
// ---------------------------------------------------------------------------
struct PP {
  const bf16 *xb, *W0, *W1, *WD0, *WD1;   // weights: [2048][Kfull] bf16 concat ih|hh
  const float *b0, *b1, *db0, *db1;
  bf16 *E0s, *E1b, *D0s, *H1b;            // [B][T][512] sequence buffers
  unsigned *flags;                         // [4][4] stride-32 u32 counters
};

#define LDS_STRIDE 2064   // 1024 bf16 cols * 2B + 16B pad (bank rotation)
#define LDS_W_BYTES (64 * LDS_STRIDE)     // 132096
#define LDS_TOTAL (LDS_W_BYTES + 8192)    // + zbuf  = 140288 <= 160K

__global__ __launch_bounds__(512, 1) void rec_persist(PP P) {
  __shared__ char lds_raw[LDS_TOTAL];
  char* wlds = lds_raw;
  float* zbuf = (float*)(lds_raw + LDS_W_BYTES);

  const int blk = blockIdx.x;
  const bool g1 = blk >= 128;
  const int lb = g1 ? blk - 128 : blk;
  const int jg = lb & 31, bg = lb >> 5;
  const int b0 = bg * 32, jh0 = jg * 16;
  const int tid = threadIdx.x, w = tid >> 6, lane = tid & 63;
  const int gate = w & 3, bt = w >> 2;
  const int arow = b0 + bt * 16 + (lane & 15);      // A-frag batch row
  const int rlds = gate * 16 + (lane & 15);         // LDS weight row
  const int brow = gate * HID + jh0 + (lane & 15);  // global weight row
  const int kb = (lane >> 4) * 8;
  // epilogue mapping: 512 threads -> 32 batches x 16 cols
  const int eb = b0 + (tid >> 8) * 16 + ((tid >> 4) & 15);
  const int ej = jh0 + (tid & 15);

  unsigned* fA = P.flags + (0 * 4 + bg) * 32;
  unsigned* fB = P.flags + (1 * 4 + bg) * 32;
  unsigned* f0 = P.flags + (2 * 4 + bg) * 32;
  unsigned* f1 = P.flags + (3 * 4 + bg) * 32;

  auto spin = [&](unsigned* f, unsigned tgt) {
    while (__hip_atomic_load(f, __ATOMIC_RELAXED, __HIP_MEMORY_SCOPE_AGENT) < tgt)
      __builtin_amdgcn_s_sleep(1);
  };
  auto cwait = [&](unsigned* fp1, unsigned t1, unsigned* fp2, unsigned t2) {
    if (tid == 0) {
      if (fp1) spin(fp1, t1);
      if (fp2) spin(fp2, t2);
      __builtin_amdgcn_fence(__ATOMIC_ACQUIRE, "agent");
    }
    __syncthreads();
  };
  auto produce = [&](unsigned* fp) {
    asm volatile("s_waitcnt vmcnt(0)" ::: "memory");
    __syncthreads();
    if (tid == 0) {
      __builtin_amdgcn_fence(__ATOMIC_RELEASE, "agent");
      __hip_atomic_fetch_add(fp, 1u, __ATOMIC_RELAXED, __HIP_MEMORY_SCOPE_AGENT);
    }
  };
  // stage this block's 64 weight rows [colOff..colOff+Kst) into LDS
  auto stage = [&](const bf16* Wb, int Kfull, int colOff, int Kst) {
    __syncthreads();
    const int upr = Kst / 8;
    for (int u = tid; u < 64 * upr; u += 512) {
      int r = u / upr, cu = u - r * upr;
      int grow = (r >> 4) * HID + jh0 + (r & 15);
      short8 v = *(const short8*)(Wb + (size_t)grow * Kfull + colOff + cu * 8);
      *(short8*)(wlds + r * LDS_STRIDE + cu * 16) = v;
    }
    __syncthreads();
  };
  // A from seq buffer [b][T][rowE], B from LDS at ldsOff (elems), iters k-steps
  auto mma_seq = [&](const bf16* seq, int rowE, int t, int ldsOff, int iters,
                     f32x4 acc) -> f32x4 {
    const bf16* ab = seq + ((size_t)arow * TSTEPS + t) * rowE;
#pragma unroll 4
    for (int i = 0; i < iters; ++i) {
      int kk = i * 32;
      short8 a = *(const short8*)(ab + kk + kb);
      short8 wv = *(const short8*)(wlds + rlds * LDS_STRIDE + (ldsOff + kk + kb) * 2);
      acc = __builtin_amdgcn_mfma_f32_16x16x32_bf16(a, wv, acc, 0, 0, 0);
    }
    return acc;
  };
  auto epilogue = [&](f32x4 acc, int t, float bi, float bf_, float bg_, float bo,
                      float& c, bf16* oseq) {
    float* zb = zbuf + (bt * 4 + gate) * 256;
#pragma unroll
    for (int r = 0; r < 4; ++r)
      zb[((lane >> 4) * 4 + r) * 16 + (lane & 15)] = acc[r];
    __syncthreads();
    const float* zq = zbuf + (tid >> 8) * 1024 + ((tid >> 4) & 15) * 16 + (tid & 15);
    float zi = zq[0] + bi, zf = zq[256] + bf_, zg = zq[512] + bg_, zo = zq[768] + bo;
    float cc = sigf(zf) * c + sigf(zi) * tanhf(zg);
    c = cc;
    float h = sigf(zo) * tanhf(cc);
    bf16 hb = __float2bfloat16(h);
    ((unsigned short*)oseq)[((size_t)eb * TSTEPS + t) * HID + ej] =
        *(unsigned short*)&hb;
  };

  if (!g1) {
    // ---------------- enc0 ----------------
    stage(P.W0, 640, 0, 640);
    float bi = P.b0[ej], bf_ = P.b0[HID + ej], bg_ = P.b0[2 * HID + ej],
          bo = P.b0[3 * HID + ej];
    float c = 0.f;
    for (int t = 0; t < TSTEPS; ++t) {
      if (t >= 1) cwait(fA, 32u * t, nullptr, 0);
      f32x4 acc = {0.f, 0.f, 0.f, 0.f};
      acc = mma_seq(P.xb, IN_DIM, t, 0, 4, acc);              // x part K=128
      if (t >= 1) acc = mma_seq(P.E0s, HID, t - 1, 128, 16, acc);
      epilogue(acc, t, bi, bf_, bg_, bo, c, P.E0s);
      produce(fA);
    }
    // ---------------- dec0 ----------------
    cwait(fB, 32u * TSTEPS, nullptr, 0);                      // z ready
    stage(P.WD0, 1024, 512, 512);                             // hh slice only
    f32x4 accz = {0.f, 0.f, 0.f, 0.f};
    {
      const bf16* zrow = P.E1b + ((size_t)arow * TSTEPS + (TSTEPS - 1)) * HID;
      const bf16* wg = P.WD0 + (size_t)brow * 1024;
#pragma unroll 4
      for (int i = 0; i < 16; ++i) {
        int kk = i * 32;
        short8 a = *(const short8*)(zrow + kk + kb);
        short8 b = *(const short8*)(wg + kk + kb);
        accz = __builtin_amdgcn_mfma_f32_16x16x32_bf16(a, b, accz, 0, 0, 0);
      }
      float bz = P.db0[brow];
#pragma unroll
      for (int r = 0; r < 4; ++r) accz[r] += bz;
    }
    c = 0.f;   // reuse state register for dec0
    for (int t = 0; t < TSTEPS; ++t) {
      if (t >= 1) cwait(f0, 32u * t, nullptr, 0);
      f32x4 acc = accz;
      if (t >= 1) acc = mma_seq(P.D0s, HID, t - 1, 0, 16, acc);
      epilogue(acc, t, 0.f, 0.f, 0.f, 0.f, c, P.D0s);
      produce(f0);
    }
  } else {
    // ---------------- enc1 ----------------
    stage(P.W1, 1024, 0, 1024);
    float bi = P.b1[ej], bf_ = P.b1[HID + ej], bg_ = P.b1[2 * HID + ej],
          bo = P.b1[3 * HID + ej];
    float c = 0.f;
    for (int t = 0; t < TSTEPS; ++t) {
      cwait(fA, 32u * (t + 1), (t >= 1) ? fB : nullptr, 32u * t);
      f32x4 acc = {0.f, 0.f, 0.f, 0.f};
      acc = mma_seq(P.E0s, HID, t, 0, 16, acc);               // x = enc0 h(t)
      if (t >= 1) acc = mma_seq(P.E1b, HID, t - 1, 512, 16, acc);
      epilogue(acc, t, bi, bf_, bg_, bo, c, P.E1b);
      produce(fB);
    }
    // ---------------- dec1 ----------------
    stage(P.WD1, 1024, 0, 1024);
    float di = P.db1[ej], df = P.db1[HID + ej], dg = P.db1[2 * HID + ej],
          dob = P.db1[3 * HID + ej];
    c = 0.f;
    for (int t = 0; t < TSTEPS; ++t) {
      cwait(f0, 32u * (t + 1), (t >= 1) ? f1 : nullptr, 32u * t);
      f32x4 acc = {0.f, 0.f, 0.f, 0.f};
      acc = mma_seq(P.D0s, HID, t, 0, 16, acc);               // x = dec0 h(t)
      if (t >= 1) acc = mma_seq(P.H1b, HID, t - 1, 512, 16, acc);
      epilogue(acc, t, di, df, dg, dob, c, P.H1b);
      produce(f1);
    }
  }
}

// ---------------------------------------------------------------------------
// Tail MFMA GEMM: out[M][N] = A[M][512] @ W[N][512]^T + bias
//   MODE 0: fp32 out, N=128 (fc)   MODE 1: relu bf16, N=512 (cls1)
//   MODE 2: fp32 out, N=128, time-shift rows (cls2)
// ---------------------------------------------------------------------------
template <int MODE>
__global__ __launch_bounds__(512) void mfma_gemm(
    const bf16* __restrict__ A, const bf16* __restrict__ W,
    const float* __restrict__ bias, void* __restrict__ out)
{
  const int n0 = blockIdx.x * 64, m0 = blockIdx.y * 128;
  const int tid = threadIdx.x, w = tid >> 6, lane = tid & 63;
  const int nq = w & 3, mh = w >> 2;
  const int mb = m0 + mh * 64;
  const int col = n0 + nq * 16 + (lane & 15);
  const int kb = (lane >> 4) * 8;
  const bf16* wrow = W + (size_t)col * HID;

  f32x4 acc[4];
#pragma unroll
  for (int i = 0; i < 4; ++i) acc[i] = (f32x4){0.f, 0.f, 0.f, 0.f};

#pragma unroll 4
  for (int kk = 0; kk < HID; kk += 32) {
    short8 bfr = *(const short8*)(wrow + kk + kb);
#pragma unroll
    for (int i = 0; i < 4; ++i) {
      short8 afr = *(const short8*)(A + (size_t)(mb + i * 16 + (lane & 15)) * HID + kk + kb);
      acc[i] = __builtin_amdgcn_mfma_f32_16x16x32_bf16(afr, bfr, acc[i], 0, 0, 0);
    }
  }
  const float bv = bias[col];
#pragma unroll
  for (int i = 0; i < 4; ++i) {
#pragma unroll
    for (int r = 0; r < 4; ++r) {
      int m = mb + i * 16 + (lane >> 4) * 4 + r;
      float v = acc[i][r] + bv;
      if (MODE == 1) {
        ((bf16*)out)[(size_t)m * HID + col] = __float2bfloat16(fmaxf(v, 0.f));
      } else if (MODE == 0) {
        ((float*)out)[(size_t)m * IN_DIM + col] = v;
      } else {
        int t = m & (TSTEPS - 1), b = m >> 8;
        if (t < TSTEPS - 1)
          ((float*)out)[((size_t)b * TSTEPS + t + 1) * IN_DIM + col] = v;
      }
    }
  }
}

// ---------------------------------------------------------------------------
extern "C" void kernel_launch(void* const* d_in, const int* in_sizes, int n_in,
                              void* d_out, int out_size, void* d_ws, size_t ws_size,
                              hipStream_t stream) {
  (void)in_sizes; (void)n_in; (void)out_size; (void)ws_size;

  const float* x        = (const float*)d_in[0];
  const float* enc_Wih0 = (const float*)d_in[1];
  const float* enc_Whh0 = (const float*)d_in[2];
  const float* enc_b0   = (const float*)d_in[3];
  const float* enc_Wih1 = (const float*)d_in[4];
  const float* enc_Whh1 = (const float*)d_in[5];
  const float* enc_b1   = (const float*)d_in[6];
  const float* dec_Wih0 = (const float*)d_in[7];
  const float* dec_Whh0 = (const float*)d_in[8];
  const float* dec_b0   = (const float*)d_in[9];
  const float* dec_Wih1 = (const float*)d_in[10];
  const float* dec_Whh1 = (const float*)d_in[11];
  const float* dec_b1   = (const float*)d_in[12];
  const float* fc_W     = (const float*)d_in[13];
  const float* fc_b     = (const float*)d_in[14];
  const float* cls1_W   = (const float*)d_in[15];
  const float* cls1_b   = (const float*)d_in[16];
  const float* cls2_W   = (const float*)d_in[17];
  const float* cls2_b   = (const float*)d_in[18];

  float* out_dec   = (float*)d_out;
  float* out_preds = (float*)d_out + (size_t)BATCH * TSTEPS * IN_DIM;

  // ---- workspace carve-up (256B aligned) ----
  char* wsp = (char*)d_ws;
  auto alloc = [&](size_t bytes) { char* p = wsp; wsp += (bytes + 255) & ~(size_t)255; return p; };
  bf16* W0   = (bf16*)alloc((size_t)GATES * 640 * 2);
  bf16* W1   = (bf16*)alloc((size_t)GATES * 1024 * 2);
  bf16* WD0  = (bf16*)alloc((size_t)GATES * 1024 * 2);
  bf16* WD1  = (bf16*)alloc((size_t)GATES * 1024 * 2);
  bf16* Wc1  = (bf16*)alloc((size_t)HID * HID * 2);
  bf16* Wc2  = (bf16*)alloc((size_t)IN_DIM * HID * 2);
  bf16* Wfc  = (bf16*)alloc((size_t)IN_DIM * HID * 2);
  bf16* xb   = (bf16*)alloc((size_t)BATCH * TSTEPS * IN_DIM * 2);
  bf16* E0s  = (bf16*)alloc((size_t)BATCH * TSTEPS * HID * 2);
  bf16* E1b  = (bf16*)alloc((size_t)BATCH * TSTEPS * HID * 2);
  bf16* D0s  = (bf16*)alloc((size_t)BATCH * TSTEPS * HID * 2);
  bf16* H1b  = (bf16*)alloc((size_t)BATCH * TSTEPS * HID * 2);
  bf16* P1b  = (bf16*)alloc((size_t)BATCH * TSTEPS * HID * 2);
  unsigned* flags = (unsigned*)alloc(512 * 4);

  // 1. zero flags (re-zeroed every call: required for graph replay)
  zero_kernel<<<dim3(2), dim3(256), 0, stream>>>((float*)flags, 512);

  // 2. fp32 -> bf16 conversions (weights concat ih|hh, x)
  auto conv = [&](const float* in, bf16* outp, int rows, int cols, int old, int ooff) {
    int n = rows * cols;
    f2b_mat<<<dim3((n + 255) / 256), dim3(256), 0, stream>>>(in, outp, rows, cols, old, ooff);
  };
  conv(enc_Wih0, W0, GATES, IN_DIM, 640, 0);
  conv(enc_Whh0, W0, GATES, HID, 640, IN_DIM);
  conv(enc_Wih1, W1, GATES, HID, 1024, 0);
  conv(enc_Whh1, W1, GATES, HID, 1024, HID);
  conv(dec_Wih0, WD0, GATES, HID, 1024, 0);
  conv(dec_Whh0, WD0, GATES, HID, 1024, HID);
  conv(dec_Wih1, WD1, GATES, HID, 1024, 0);
  conv(dec_Whh1, WD1, GATES, HID, 1024, HID);
  conv(cls1_W, Wc1, HID, HID, HID, 0);
  conv(cls2_W, Wc2, IN_DIM, HID, HID, 0);
  conv(fc_W, Wfc, IN_DIM, HID, HID, 0);
  conv(x, xb, BATCH * TSTEPS, IN_DIM, IN_DIM, 0);

  // 3. persistent recurrence (cooperative: 256 blocks = 256 CUs, 1/CU)
  PP P;
  P.xb = xb; P.W0 = W0; P.W1 = W1; P.WD0 = WD0; P.WD1 = WD1;
  P.b0 = enc_b0; P.b1 = enc_b1; P.db0 = dec_b0; P.db1 = dec_b1;
  P.E0s = E0s; P.E1b = E1b; P.D0s = D0s; P.H1b = H1b;
  P.flags = flags;
  void* args[] = {&P};
  (void)hipLaunchCooperativeKernel(reinterpret_cast<void*>(rec_persist),
                                   dim3(256), dim3(512), args, 0, stream);

  // 4. tails
  mfma_gemm<1><<<dim3(HID / 64, (BATCH * TSTEPS) / 128), dim3(512), 0, stream>>>(
      E1b, Wc1, cls1_b, P1b);
  mfma_gemm<2><<<dim3(IN_DIM / 64, (BATCH * TSTEPS) / 128), dim3(512), 0, stream>>>(
      P1b, Wc2, cls2_b, out_preds);
  mfma_gemm<0><<<dim3(IN_DIM / 64, (BATCH * TSTEPS) / 128), dim3(512), 0, stream>>>(
      H1b, Wfc, fc_b, out_dec);

  // 5. preds[:,0,:] = x[:,1,:]
  copy_pred0_kernel<<<dim3((BATCH * IN_DIM + 255) / 256), dim3(256), 0, stream>>>(x, out_preds);
}